// Round 1
// baseline (6323.399 us; speedup 1.0000x reference)
//
#include <hip/hip_runtime.h>
#include <stdint.h>
#include <stddef.h>

// Routed 2-cell LSTM, B=64, S=512, E=H=256.
// Persistent-grid design: 64 workgroups, each owns 32 gate rows (one cell,
// 8 hidden units x 4 gates) of the 2048 global rows, weights LDS-resident as
// split-bf16 MFMA A-fragments. Per step: MFMA (16x16x32 bf16) computes
// gates for all 64 tokens; the owning wg applies the LSTM pointwise update
// for tokens routed to its cell and publishes h as hi/lo bf16 B-fragments +
// c (fp32) to double-buffered global scratch; monotonic atomic grid barrier.

#define BB   64
#define SS   512
#define EE   256
#define HH   256
#define G4   1024
#define NWG  64
#define TPB  256

typedef __attribute__((ext_vector_type(8))) short short8;
typedef __attribute__((ext_vector_type(4))) float f32x4;

__device__ __forceinline__ unsigned short f2bf(float f){
  union { float f; unsigned u; } v; v.f = f;
  return (unsigned short)((v.u + 0x7fffu + ((v.u >> 16) & 1u)) >> 16);
}
__device__ __forceinline__ float bf2f(unsigned short s){
  union { float f; unsigned u; } v; v.u = ((unsigned)s) << 16;
  return v.f;
}

// ws layout (bytes):
// [0,256)                 : grid-barrier counter
// [256, 256+131072)       : h fragments: 2 parities x [2 half][4 nt][8 kc][64 lane][8 e] ushort
// [131328, 131328+131072) : c state: 2 parities x [64][256] float
#define WS_HF_OFF 256
#define WS_C_OFF  (256 + 131072)
#define WS_BYTES  (256 + 131072 + 131072)

__global__ void zero_ws_kernel(int* ws){
  const int n = WS_BYTES / 4;
  for (int i = blockIdx.x * blockDim.x + threadIdx.x; i < n; i += gridDim.x * blockDim.x)
    ws[i] = 0;
}

__global__ __launch_bounds__(TPB, 1)
void mlstm_kernel(const int* __restrict__ input, const int* __restrict__ assign,
                  const float* __restrict__ emb, const float* __restrict__ Wih,
                  const float* __restrict__ Whh, const float* __restrict__ bih,
                  const float* __restrict__ bhh, float* __restrict__ out,
                  char* __restrict__ ws)
{
  // A-fragment layout: [rt][kc][lane][e], lane row = lane&15 (+16*rt), k = kc*32 + (lane>>4)*8 + e
  __shared__ unsigned short sWhi[2][16][64][8]; // 32 KB: hi(W) over K=512 (x:0..255 = W_ih, h:256..511 = W_hh)
  __shared__ unsigned short sWlo[2][8][64][8];  // 16 KB: lo(W_hh) over h-part only
  __shared__ float sGate[32][64];               // 8 KB: [wg row][token]

  const int tid  = threadIdx.x;
  const int lane = tid & 63;
  const int lg   = lane >> 4;     // lanegroup 0..3
  const int lc   = lane & 15;
  const int wv   = tid >> 6;      // wave 0..3
  const int wg   = blockIdx.x;    // 0..63
  const int cell = wg >> 5;       // 0..1
  const int jset = wg & 31;       // owns hidden units jset*8 .. jset*8+7
  const int rt   = wv >> 1;       // row-tile 0..1 (rows rt*16..rt*16+15)
  const int nt0  = (wv & 1) * 2;  // this wave handles token tiles nt0, nt0+1

  int* cnt = (int*)ws;
  unsigned short* hf = (unsigned short*)(ws + WS_HF_OFF);
  float* cbuf = (float*)(ws + WS_C_OFF);

  // ---- stage split-bf16 weights into LDS (one-time) ----
  for (int fi = wv; fi < 48; fi += 4){
    if (fi < 32){
      const int frt = fi >> 4, kc = fi & 15;
      const int wrow = frt * 16 + lc;                       // 0..31: gate = wrow>>3, j = wrow&7
      const int grow = (wrow >> 3) * HH + jset * 8 + (wrow & 7);
      const int k = kc * 32 + lg * 8;
      const float* src = (k < EE) ? (Wih + ((size_t)cell * G4 + grow) * EE + k)
                                  : (Whh + ((size_t)cell * G4 + grow) * HH + (k - EE));
      short8 v;
      #pragma unroll
      for (int e = 0; e < 8; ++e) v[e] = (short)f2bf(src[e]);
      *(short8*)&sWhi[frt][kc][lane][0] = v;
    } else {
      const int f2 = fi - 32;
      const int frt = f2 >> 3, kch = f2 & 7;
      const int wrow = frt * 16 + lc;
      const int grow = (wrow >> 3) * HH + jset * 8 + (wrow & 7);
      const int k = kch * 32 + lg * 8;
      const float* src = Whh + ((size_t)cell * G4 + grow) * HH + k;
      short8 v;
      #pragma unroll
      for (int e = 0; e < 8; ++e){
        const float w = src[e];
        const unsigned short hi = f2bf(w);
        v[e] = (short)f2bf(w - bf2f(hi));
      }
      *(short8*)&sWlo[frt][kch][lane][0] = v;
    }
  }

  // per-lane bias for its 4 accumulator rows (C/D: row = (lane>>4)*4+q + 16*rt)
  float biasr[4];
  #pragma unroll
  for (int q = 0; q < 4; ++q){
    const int wrow = rt * 16 + lg * 4 + q;
    const int grow = (wrow >> 3) * HH + jset * 8 + (wrow & 7);
    biasr[q] = bih[cell * G4 + grow] + bhh[cell * G4 + grow];
  }
  __syncthreads();

  const int b0  = tid & 63;   // update-phase batch element
  const int jl0 = tid >> 6;   // update-phase j: jl0 and jl0+4

  for (int t = 0; t < SS; ++t){
    const int par = t & 1;
    const unsigned short* hfr = hf + (size_t)par * 32768;
    unsigned short* hfw = hf + (size_t)(par ^ 1) * 32768;
    const float* cr = cbuf + (size_t)par * 16384;
    float* cw = cbuf + (size_t)(par ^ 1) * 16384;

    // routing info for the update phase
    const int toku = input[b0 * SS + t];
    const int au   = assign[toku];

    // ---- gather x_t B-fragments from embeddings (hi bf16 only) ----
    short8 xv[2][8];
    #pragma unroll
    for (int ni = 0; ni < 2; ++ni){
      const int bb = (nt0 + ni) * 16 + lc;
      const int tok = input[bb * SS + t];
      const float* ep = emb + (size_t)tok * EE + lg * 8;
      #pragma unroll
      for (int kc = 0; kc < 8; ++kc){
        const f32x4 a = *(const f32x4*)(ep + kc * 32);
        const f32x4 b = *(const f32x4*)(ep + kc * 32 + 4);
        short8 v;
        v[0]=(short)f2bf(a[0]); v[1]=(short)f2bf(a[1]); v[2]=(short)f2bf(a[2]); v[3]=(short)f2bf(a[3]);
        v[4]=(short)f2bf(b[0]); v[5]=(short)f2bf(b[1]); v[6]=(short)f2bf(b[2]); v[7]=(short)f2bf(b[3]);
        xv[ni][kc] = v;
      }
    }

    // ---- load h_t B-fragments (hi+lo) ----
    short8 hv[2][8][2];
    #pragma unroll
    for (int ni = 0; ni < 2; ++ni){
      #pragma unroll
      for (int kch = 0; kch < 8; ++kch){
        const size_t off = ((size_t)((nt0 + ni) * 8 + kch) * 64 + lane) * 8;
        hv[ni][kch][0] = *(const short8*)(hfr + off);           // hi
        hv[ni][kch][1] = *(const short8*)(hfr + 16384 + off);   // lo
      }
    }

    f32x4 acc[2];
    acc[0][0]=biasr[0]; acc[0][1]=biasr[1]; acc[0][2]=biasr[2]; acc[0][3]=biasr[3];
    acc[1] = acc[0];

    // x-part: Whi . xhi
    #pragma unroll
    for (int kc = 0; kc < 8; ++kc){
      const short8 ah = *(const short8*)&sWhi[rt][kc][lane][0];
      acc[0] = __builtin_amdgcn_mfma_f32_16x16x32_bf16(ah, xv[0][kc], acc[0], 0, 0, 0);
      acc[1] = __builtin_amdgcn_mfma_f32_16x16x32_bf16(ah, xv[1][kc], acc[1], 0, 0, 0);
    }
    // h-part: Whi.hhi + Whi.hlo + Wlo.hhi  (~fp32 accuracy)
    #pragma unroll
    for (int kch = 0; kch < 8; ++kch){
      const short8 ah = *(const short8*)&sWhi[rt][8 + kch][lane][0];
      const short8 al = *(const short8*)&sWlo[rt][kch][lane][0];
      acc[0] = __builtin_amdgcn_mfma_f32_16x16x32_bf16(ah, hv[0][kch][0], acc[0], 0, 0, 0);
      acc[1] = __builtin_amdgcn_mfma_f32_16x16x32_bf16(ah, hv[1][kch][0], acc[1], 0, 0, 0);
      acc[0] = __builtin_amdgcn_mfma_f32_16x16x32_bf16(ah, hv[0][kch][1], acc[0], 0, 0, 0);
      acc[1] = __builtin_amdgcn_mfma_f32_16x16x32_bf16(ah, hv[1][kch][1], acc[1], 0, 0, 0);
      acc[0] = __builtin_amdgcn_mfma_f32_16x16x32_bf16(al, hv[0][kch][0], acc[0], 0, 0, 0);
      acc[1] = __builtin_amdgcn_mfma_f32_16x16x32_bf16(al, hv[1][kch][0], acc[1], 0, 0, 0);
    }

    // gates -> LDS for cross-lane (i,f,g,o) regrouping
    #pragma unroll
    for (int ni = 0; ni < 2; ++ni){
      #pragma unroll
      for (int q = 0; q < 4; ++q)
        sGate[rt * 16 + lg * 4 + q][(nt0 + ni) * 16 + lc] = acc[ni][q];
    }
    __syncthreads();

    // ---- pointwise LSTM update for tokens routed to this cell ----
    if (au == cell){
      #pragma unroll
      for (int uu = 0; uu < 2; ++uu){
        const int jl = jl0 + uu * 4;                   // 0..7
        const float gi = sGate[jl][b0];
        const float gf = sGate[8 + jl][b0];
        const float gg = sGate[16 + jl][b0];
        const float go = sGate[24 + jl][b0];
        const int jg = jset * 8 + jl;
        const float cold = cr[b0 * 256 + jg];
        const float si = 1.f / (1.f + __expf(-gi));
        const float sf = 1.f / (1.f + __expf(-gf));
        const float so = 1.f / (1.f + __expf(-go));
        const float cn = sf * cold + si * tanhf(gg);
        const float hn = so * tanhf(cn);
        if (t < SS - 1){
          cw[b0 * 256 + jg] = cn;
          const unsigned short hhi = f2bf(hn);
          const unsigned short hlo = f2bf(hn - bf2f(hhi));
          const size_t hoff = ((size_t)((b0 >> 4) * 8 + (jg >> 5)) * 64
                               + ((jg & 31) >> 3) * 16 + (b0 & 15)) * 8 + (jg & 7);
          hfw[hoff] = hhi;
          hfw[16384 + hoff] = hlo;
        } else {
          out[b0 * 512 + jg]       = hn;
          out[b0 * 512 + 256 + jg] = cn;
        }
      }
    }

    // ---- grid barrier (monotonic counter; all 64 blocks co-resident) ----
    if (t < SS - 1){
      __syncthreads();
      if (tid == 0){
        __threadfence();                 // device-scope release of h/c stores
        atomicAdd(cnt, 1);
        const int target = NWG * (t + 1);
        while (__hip_atomic_load(cnt, __ATOMIC_ACQUIRE, __HIP_MEMORY_SCOPE_AGENT) < target)
          __builtin_amdgcn_s_sleep(1);
      }
      __syncthreads();
    }
  }
}

extern "C" void kernel_launch(void* const* d_in, const int* in_sizes, int n_in,
                              void* d_out, int out_size, void* d_ws, size_t ws_size,
                              hipStream_t stream)
{
  const int*   input  = (const int*)  d_in[0];
  const int*   assign = (const int*)  d_in[1];
  const float* emb    = (const float*)d_in[2];
  const float* Wih    = (const float*)d_in[3];
  const float* Whh    = (const float*)d_in[4];
  const float* bih    = (const float*)d_in[5];
  const float* bhh    = (const float*)d_in[6];
  float* out = (float*)d_out;
  char*  ws  = (char*)d_ws;

  zero_ws_kernel<<<64, TPB, 0, stream>>>((int*)ws);
  mlstm_kernel<<<NWG, TPB, 0, stream>>>(input, assign, emb, Wih, Whh, bih, bhh, out, ws);
}

// Round 2
// 6194.707 us; speedup vs baseline: 1.0208x; 1.0208x over previous
//
#include <hip/hip_runtime.h>
#include <stdint.h>
#include <stddef.h>

// Routed 2-cell LSTM, B=64, S=512, E=H=256.
// 16 persistent wgs x 512 threads. wg owns 16 hidden units j in [wg*16,wg*16+16)
// for BOTH cells: computes 128 gate rows (2 cells x 4 gates x 16 j) for all 64
// tokens via 16x16x32 bf16 MFMA (split hi/lo bf16 for the h-path), selects the
// routed cell per token, updates c (LDS-resident) and publishes its h-slice as
// B-fragments to global. Weights register-resident; x/emb and input/assign
// prefetched ahead; 16-flag store-release barrier per step.

#define BB   64
#define SS   512
#define EE   256
#define HH   256
#define G4   1024
#define NWG  16
#define TPB  512

typedef __attribute__((ext_vector_type(8))) short short8;
typedef __attribute__((ext_vector_type(4))) float f32x4;

__device__ __forceinline__ unsigned short f2bf(float f){
  union { float f; unsigned u; } v; v.f = f;
  return (unsigned short)((v.u + 0x7fffu + ((v.u >> 16) & 1u)) >> 16);
}
__device__ __forceinline__ float bf2f(unsigned short s){
  union { float f; unsigned u; } v; v.u = ((unsigned)s) << 16;
  return v.f;
}

// ws layout (bytes):
// [0, 1024)            : 16 per-wg step flags, stride 64 B
// [1024, 1024+131072)  : h fragments, 2 parities x [2 half][8 kch][4 lg][4 ct][16 lc][8 e] ushort
#define WS_H_OFF 1024

__global__ void zero_flags_kernel(int* ws){
  if (threadIdx.x < 256) ws[threadIdx.x] = 0;
}

__global__ __launch_bounds__(TPB, 2)
void mlstm_kernel(const int* __restrict__ input, const int* __restrict__ assign,
                  const float* __restrict__ emb, const float* __restrict__ Wih,
                  const float* __restrict__ Whh, const float* __restrict__ bih,
                  const float* __restrict__ bhh, float* __restrict__ out,
                  char* __restrict__ ws)
{
  __shared__ __align__(16) unsigned short sX[2][8][4][4][16][8]; // 64 KB x double buffer (x B-frags)
  __shared__ float sGate[128][68];                               // 34.8 KB (padded: 68)
  __shared__ float sC[64][16];                                   // 4 KB c state (wg-local!)
  __shared__ int sTok[3][64];
  __shared__ int sAsg[3][64];

  const int tid  = threadIdx.x;
  const int lane = tid & 63;
  const int lg   = lane >> 4;
  const int lc   = lane & 15;
  const int wv   = tid >> 6;       // 0..7
  const int wg   = blockIdx.x;     // 0..15
  const int cell = wv >> 2;        // wave's row-tile: cell
  const int gate = wv & 3;         // wave's row-tile: gate

  int* flags = (int*)ws;
  unsigned short* hbuf = (unsigned short*)(ws + WS_H_OFF);

  // ---- load register-resident A-fragments (one-time) ----
  // A row m = lc -> W row = cell*G4? no: row index within [4H): gate*HH + wg*16 + lc
  const size_t rowA = (size_t)cell * G4 + (size_t)gate * HH + wg * 16 + lc;
  short8 aHiH[8], aLoH[8], aHiX[8];
  {
    const float* ph = Whh + rowA * HH + lg * 8;
    const float* px = Wih + rowA * EE + lg * 8;
    #pragma unroll
    for (int kc = 0; kc < 8; ++kc){
      const f32x4 u = *(const f32x4*)(ph + kc * 32);
      const f32x4 v = *(const f32x4*)(ph + kc * 32 + 4);
      short8 hi, lo;
      #pragma unroll
      for (int e = 0; e < 4; ++e){
        const float w0 = u[e], w1 = v[e];
        const unsigned short h0 = f2bf(w0), h1 = f2bf(w1);
        hi[e] = (short)h0;     lo[e] = (short)f2bf(w0 - bf2f(h0));
        hi[4+e] = (short)h1;   lo[4+e] = (short)f2bf(w1 - bf2f(h1));
      }
      aHiH[kc] = hi; aLoH[kc] = lo;
      const f32x4 a = *(const f32x4*)(px + kc * 32);
      const f32x4 b = *(const f32x4*)(px + kc * 32 + 4);
      short8 xh;
      #pragma unroll
      for (int e = 0; e < 4; ++e){ xh[e] = (short)f2bf(a[e]); xh[4+e] = (short)f2bf(b[e]); }
      aHiX[kc] = xh;
    }
  }
  float biasr[4];
  #pragma unroll
  for (int q = 0; q < 4; ++q){
    const int idx = cell * G4 + gate * HH + wg * 16 + lg * 4 + q;
    biasr[q] = bih[idx] + bhh[idx];
  }

  // ---- prologue: tokens for t=0,1; x fragments for t=0 ----
  if (tid < 64){
    const int t0 = input[tid * SS + 0];
    sTok[0][tid] = t0; sAsg[0][tid] = assign[t0];
    const int t1 = input[tid * SS + 1];
    sTok[1][tid] = t1; sAsg[1][tid] = assign[t1];
  }
  __syncthreads();

  const int gkc = tid >> 6, glg = (tid >> 4) & 3, glc = tid & 15;
  auto GATHER = [&](int buf, int slot){
    #pragma unroll
    for (int ct = 0; ct < 4; ++ct){
      const int b = ct * 16 + glc;
      const int tok = sTok[slot][b];
      const float* ep = emb + (size_t)tok * EE + gkc * 32 + glg * 8;
      const f32x4 u = *(const f32x4*)ep;
      const f32x4 v = *(const f32x4*)(ep + 4);
      short8 x8;
      #pragma unroll
      for (int e = 0; e < 4; ++e){ x8[e] = (short)f2bf(u[e]); x8[4+e] = (short)f2bf(v[e]); }
      *(short8*)&sX[buf][gkc][glg][ct][glc][0] = x8;
    }
  };
  GATHER(0, 0);
  __syncthreads();

  const int ujl = tid & 15;        // update-phase j-local
  const int ubb = tid >> 4;        // update-phase batch (handles ubb, ubb+32)

  for (int t = 0; t < SS; ++t){
    const int cb = t & 1, nb = cb ^ 1;
    const int s1 = (t + 1) % 3, s2 = (t + 2) % 3;

    // ---- prefetch: tokens t+2, x fragments t+1 (off critical path) ----
    if (t + 2 < SS && tid < 64){
      const int tk = input[tid * SS + (t + 2)];
      sTok[s2][tid] = tk; sAsg[s2][tid] = assign[tk];
    }
    if (t + 1 < SS) GATHER(nb, s1);

    // ---- gates: x-part + h-part MFMAs ----
    f32x4 acc0, acc1, acc2, acc3;
    acc0[0]=biasr[0]; acc0[1]=biasr[1]; acc0[2]=biasr[2]; acc0[3]=biasr[3];
    acc1 = acc0; acc2 = acc0; acc3 = acc0;

    #pragma unroll
    for (int kc = 0; kc < 8; ++kc){
      const short8 b0 = *(const short8*)&sX[cb][kc][lg][0][lc][0];
      const short8 b1 = *(const short8*)&sX[cb][kc][lg][1][lc][0];
      const short8 b2 = *(const short8*)&sX[cb][kc][lg][2][lc][0];
      const short8 b3 = *(const short8*)&sX[cb][kc][lg][3][lc][0];
      acc0 = __builtin_amdgcn_mfma_f32_16x16x32_bf16(aHiX[kc], b0, acc0, 0, 0, 0);
      acc1 = __builtin_amdgcn_mfma_f32_16x16x32_bf16(aHiX[kc], b1, acc1, 0, 0, 0);
      acc2 = __builtin_amdgcn_mfma_f32_16x16x32_bf16(aHiX[kc], b2, acc2, 0, 0, 0);
      acc3 = __builtin_amdgcn_mfma_f32_16x16x32_bf16(aHiX[kc], b3, acc3, 0, 0, 0);
    }

    if (t > 0){
      const unsigned short* hr = hbuf + (size_t)(t & 1) * 32768;
      #pragma unroll
      for (int kch = 0; kch < 8; ++kch){
        const unsigned short* p = hr + ((kch * 4 + lg) * 4) * 128 + lc * 8;
        const short8 hh0 = *(const short8*)(p);
        const short8 hh1 = *(const short8*)(p + 128);
        const short8 hh2 = *(const short8*)(p + 256);
        const short8 hh3 = *(const short8*)(p + 384);
        const short8 hl0 = *(const short8*)(p + 16384);
        const short8 hl1 = *(const short8*)(p + 16384 + 128);
        const short8 hl2 = *(const short8*)(p + 16384 + 256);
        const short8 hl3 = *(const short8*)(p + 16384 + 384);
        acc0 = __builtin_amdgcn_mfma_f32_16x16x32_bf16(aHiH[kch], hh0, acc0, 0, 0, 0);
        acc1 = __builtin_amdgcn_mfma_f32_16x16x32_bf16(aHiH[kch], hh1, acc1, 0, 0, 0);
        acc2 = __builtin_amdgcn_mfma_f32_16x16x32_bf16(aHiH[kch], hh2, acc2, 0, 0, 0);
        acc3 = __builtin_amdgcn_mfma_f32_16x16x32_bf16(aHiH[kch], hh3, acc3, 0, 0, 0);
        acc0 = __builtin_amdgcn_mfma_f32_16x16x32_bf16(aHiH[kch], hl0, acc0, 0, 0, 0);
        acc1 = __builtin_amdgcn_mfma_f32_16x16x32_bf16(aHiH[kch], hl1, acc1, 0, 0, 0);
        acc2 = __builtin_amdgcn_mfma_f32_16x16x32_bf16(aHiH[kch], hl2, acc2, 0, 0, 0);
        acc3 = __builtin_amdgcn_mfma_f32_16x16x32_bf16(aHiH[kch], hl3, acc3, 0, 0, 0);
        acc0 = __builtin_amdgcn_mfma_f32_16x16x32_bf16(aLoH[kch], hh0, acc0, 0, 0, 0);
        acc1 = __builtin_amdgcn_mfma_f32_16x16x32_bf16(aLoH[kch], hh1, acc1, 0, 0, 0);
        acc2 = __builtin_amdgcn_mfma_f32_16x16x32_bf16(aLoH[kch], hh2, acc2, 0, 0, 0);
        acc3 = __builtin_amdgcn_mfma_f32_16x16x32_bf16(aLoH[kch], hh3, acc3, 0, 0, 0);
      }
    }

    // ---- gate exchange ----
    #pragma unroll
    for (int q = 0; q < 4; ++q){
      const int row = wv * 16 + lg * 4 + q;
      sGate[row][0 * 16 + lc] = acc0[q];
      sGate[row][1 * 16 + lc] = acc1[q];
      sGate[row][2 * 16 + lc] = acc2[q];
      sGate[row][3 * 16 + lc] = acc3[q];
    }
    __syncthreads();

    // ---- pointwise LSTM update (routed select), publish h ----
    unsigned short* hw = hbuf + (size_t)((t & 1) ^ 1) * 32768;
    #pragma unroll
    for (int half = 0; half < 2; ++half){
      const int b = ubb + half * 32;
      const int a = sAsg[t % 3][b];
      const int rb = a * 64 + ujl;
      const float gi = sGate[rb][b];
      const float gf = sGate[rb + 16][b];
      const float gg = sGate[rb + 32][b];
      const float go = sGate[rb + 48][b];
      const float cold = (t == 0) ? 0.f : sC[b][ujl];
      const float si = 1.f / (1.f + __expf(-gi));
      const float sf = 1.f / (1.f + __expf(-gf));
      const float so = 1.f / (1.f + __expf(-go));
      const float cn = sf * cold + si * tanhf(gg);
      const float hn = so * tanhf(cn);
      const int j = wg * 16 + ujl;
      if (t < SS - 1){
        sC[b][ujl] = cn;
        const int off = ((((j >> 5) * 4 + ((j >> 3) & 3)) * 4 + (b >> 4)) * 16 + (b & 15)) * 8 + (j & 7);
        const unsigned short hhi = f2bf(hn);
        hw[off] = hhi;
        hw[16384 + off] = f2bf(hn - bf2f(hhi));
      } else {
        out[b * 512 + j]       = hn;
        out[b * 512 + 256 + j] = cn;
      }
    }

    // ---- flag barrier (release h, wait for all 16 wgs) ----
    if (t < SS - 1){
      __threadfence();              // drain this thread's h stores to device scope
      __syncthreads();              // all threads drained
      if (tid == 0)
        __hip_atomic_store(&flags[wg * 16], t + 1, __ATOMIC_RELEASE, __HIP_MEMORY_SCOPE_AGENT);
      if (wv == 0){
        const int need = t + 1;
        int fl = need;
        do {
          if (lane < NWG)
            fl = __hip_atomic_load(&flags[lane * 16], __ATOMIC_RELAXED, __HIP_MEMORY_SCOPE_AGENT);
        } while (__ballot(fl < need));
        __threadfence();            // acquire: invalidate stale h lines
      }
      __syncthreads();
    }
  }
}

extern "C" void kernel_launch(void* const* d_in, const int* in_sizes, int n_in,
                              void* d_out, int out_size, void* d_ws, size_t ws_size,
                              hipStream_t stream)
{
  const int*   input  = (const int*)  d_in[0];
  const int*   assign = (const int*)  d_in[1];
  const float* emb    = (const float*)d_in[2];
  const float* Wih    = (const float*)d_in[3];
  const float* Whh    = (const float*)d_in[4];
  const float* bih    = (const float*)d_in[5];
  const float* bhh    = (const float*)d_in[6];
  float* out = (float*)d_out;
  char*  ws  = (char*)d_ws;

  zero_flags_kernel<<<1, 256, 0, stream>>>((int*)ws);
  mlstm_kernel<<<NWG, TPB, 0, stream>>>(input, assign, emb, Wih, Whh, bih, bhh, out, ws);
}

// Round 3
// 4718.355 us; speedup vs baseline: 1.3402x; 1.3129x over previous
//
#include <hip/hip_runtime.h>
#include <stdint.h>
#include <stddef.h>

// Routed 2-cell LSTM, B=64, S=512, E=H=256.
// 16 persistent wgs x 512 threads; wg owns 16 hidden units for BOTH cells.
// Cross-wg h exchange via system-scope (sc0 sc1) loads/stores — coherent at
// the memory-side Infinity Cache, NO agent fences (no L2 wbl2/inv per step).
// h staged once per wg into LDS; MFMA B-frags via swizzled ds_read_b128.

#define BB   64
#define SS   512
#define EE   256
#define HH   256
#define G4   1024
#define NWG  16
#define TPB  512

typedef __attribute__((ext_vector_type(8))) short short8;
typedef __attribute__((ext_vector_type(4))) float f32x4;

__device__ __forceinline__ unsigned short f2bf(float f){
  union { float f; unsigned u; } v; v.f = f;
  return (unsigned short)((v.u + 0x7fffu + ((v.u >> 16) & 1u)) >> 16);
}
__device__ __forceinline__ float bf2f(unsigned short s){
  union { float f; unsigned u; } v; v.u = ((unsigned)s) << 16;
  return v.f;
}
// LDS bank swizzle: XOR lg (byte bits 10-11) into lc-high (bits 6-7)
__device__ __forceinline__ int swz(int byte){ return byte ^ (((byte >> 10) & 3) << 6); }

// ws: [0,1024) flags (16 x stride 64B); [1024, +131072) h frags 2 parities x 64KB
#define WS_H_OFF 1024

__global__ void zero_flags_kernel(int* ws){
  if (threadIdx.x < 256) ws[threadIdx.x] = 0;
}

__global__ __launch_bounds__(TPB, 2)
void mlstm_kernel(const int* __restrict__ input, const int* __restrict__ assign,
                  const float* __restrict__ emb, const float* __restrict__ Wih,
                  const float* __restrict__ Whh, const float* __restrict__ bih,
                  const float* __restrict__ bhh, float* __restrict__ out,
                  char* __restrict__ ws)
{
  __shared__ __align__(16) unsigned short sH[32768];  // 64 KB: staged h (hi 32KB | lo 32KB), swizzled
  __shared__ __align__(16) unsigned short sX[16384];  // 32 KB: x B-frags (single buffer), swizzled
  __shared__ float sGate[128][66];                    // 33 KB
  __shared__ float sC[64][16];                        // 4 KB  (c state, wg-local)
  __shared__ int sTok[3][64];
  __shared__ int sAsg[3][64];

  const int tid  = threadIdx.x;
  const int lane = tid & 63;
  const int lg   = lane >> 4;
  const int lc   = lane & 15;
  const int wv   = tid >> 6;       // 0..7
  const int wg   = blockIdx.x;     // 0..15
  const int cell = wv >> 2;
  const int gate = wv & 3;

  int* flags = (int*)ws;
  unsigned short* hbuf = (unsigned short*)(ws + WS_H_OFF);

  // ---- register-resident split-bf16 weight A-fragments (one-time) ----
  const size_t rowA = (size_t)cell * G4 + (size_t)gate * HH + wg * 16 + lc;
  short8 aHiH[8], aLoH[8], aHiX[8];
  {
    const float* ph = Whh + rowA * HH + lg * 8;
    const float* px = Wih + rowA * EE + lg * 8;
    #pragma unroll
    for (int kc = 0; kc < 8; ++kc){
      const f32x4 u = *(const f32x4*)(ph + kc * 32);
      const f32x4 v = *(const f32x4*)(ph + kc * 32 + 4);
      short8 hi, lo;
      #pragma unroll
      for (int e = 0; e < 4; ++e){
        const float w0 = u[e], w1 = v[e];
        const unsigned short h0 = f2bf(w0), h1 = f2bf(w1);
        hi[e] = (short)h0;   lo[e] = (short)f2bf(w0 - bf2f(h0));
        hi[4+e] = (short)h1; lo[4+e] = (short)f2bf(w1 - bf2f(h1));
      }
      aHiH[kc] = hi; aLoH[kc] = lo;
      const f32x4 a = *(const f32x4*)(px + kc * 32);
      const f32x4 b = *(const f32x4*)(px + kc * 32 + 4);
      short8 xh;
      #pragma unroll
      for (int e = 0; e < 4; ++e){ xh[e] = (short)f2bf(a[e]); xh[4+e] = (short)f2bf(b[e]); }
      aHiX[kc] = xh;
    }
  }
  float biasr[4];
  #pragma unroll
  for (int q = 0; q < 4; ++q){
    const int idx = cell * G4 + gate * HH + wg * 16 + lg * 4 + q;
    biasr[q] = bih[idx] + bhh[idx];
  }

  // gather-thread mapping
  const int gkc = tid >> 6, glg = (tid >> 4) & 3, glc = tid & 15;
  // update-thread mapping: thread -> (batch ub, j-pair uj2)
  const int ub  = tid >> 3;
  const int uj2 = (tid & 7) * 2;

  // ---- prologue: tokens slots 0,1; x frags for t=0 ----
  if (tid < 64){
    const int t0 = input[tid * SS];     sTok[0][tid] = t0; sAsg[0][tid] = assign[t0];
    const int t1 = input[tid * SS + 1]; sTok[1][tid] = t1; sAsg[1][tid] = assign[t1];
  }
  __syncthreads();
  {
    #pragma unroll
    for (int ct = 0; ct < 4; ++ct){
      const int tok = sTok[0][ct * 16 + glc];
      const float* ep = emb + (size_t)tok * EE + gkc * 32 + glg * 8;
      const f32x4 u = *(const f32x4*)ep;
      const f32x4 v = *(const f32x4*)(ep + 4);
      short8 x8;
      #pragma unroll
      for (int e = 0; e < 4; ++e){ x8[e] = (short)f2bf(u[e]); x8[4+e] = (short)f2bf(v[e]); }
      const int byte = ((gkc * 4 + glg) * 4 + ct) * 256 + glc * 16;
      *(short8*)((char*)sX + swz(byte)) = x8;
    }
  }
  __syncthreads();

  for (int t = 0; t < SS; ++t){
    const int s1 = (t + 1) % 3, s2 = (t + 2) % 3;

    // ---- A: issue system-scope h loads (cooperative full-buffer copy) ----
    short8 hcp[8];
    if (t > 0){
      const unsigned short* hr = hbuf + (size_t)(t & 1) * 32768;
      #pragma unroll
      for (int i = 0; i < 8; ++i){
        const unsigned short* p = hr + (i * 512 + tid) * 8;
        asm volatile("global_load_dwordx4 %0, %1, off sc0 sc1"
                     : "=v"(hcp[i]) : "v"(p) : "memory");
      }
    }

    // ---- B: x-part MFMAs (overlap h-load latency) ----
    f32x4 acc[4];
    #pragma unroll
    for (int ct = 0; ct < 4; ++ct){
      acc[ct][0] = biasr[0]; acc[ct][1] = biasr[1];
      acc[ct][2] = biasr[2]; acc[ct][3] = biasr[3];
    }
    #pragma unroll
    for (int kc = 0; kc < 8; ++kc){
      const int bb = (kc * 4 + lg) * 1024 + lc * 16;
      #pragma unroll
      for (int ct = 0; ct < 4; ++ct){
        const short8 bx = *(const short8*)((const char*)sX + swz(bb + ct * 256));
        acc[ct] = __builtin_amdgcn_mfma_f32_16x16x32_bf16(aHiX[kc], bx, acc[ct], 0, 0, 0);
      }
    }

    // ---- C: stage h into LDS ----
    if (t > 0){
      asm volatile("s_waitcnt vmcnt(0)" ::: "memory");
      __builtin_amdgcn_sched_barrier(0);
      #pragma unroll
      for (int i = 0; i < 8; ++i)
        *(short8*)((char*)sH + swz((i * 512 + tid) * 16)) = hcp[i];
      __syncthreads();
    }

    // ---- D: gather x(t+1) to regs; prefetch tokens t+2 ----
    short8 xr[4];
    if (t + 1 < SS){
      if (tid < 64 && t + 2 < SS){
        const int tk = input[tid * SS + (t + 2)];
        sTok[s2][tid] = tk; sAsg[s2][tid] = assign[tk];
      }
      #pragma unroll
      for (int ct = 0; ct < 4; ++ct){
        const int tok = sTok[s1][ct * 16 + glc];
        const float* ep = emb + (size_t)tok * EE + gkc * 32 + glg * 8;
        const f32x4 u = *(const f32x4*)ep;
        const f32x4 v = *(const f32x4*)(ep + 4);
        short8 x8;
        #pragma unroll
        for (int e = 0; e < 4; ++e){ x8[e] = (short)f2bf(u[e]); x8[4+e] = (short)f2bf(v[e]); }
        xr[ct] = x8;
      }
    }

    // ---- E: h-part MFMAs from LDS ----
    if (t > 0){
      #pragma unroll
      for (int kch = 0; kch < 8; ++kch){
        const int base = (kch * 4 + lg) * 1024 + lc * 16;
        short8 hh[4], hl[4];
        #pragma unroll
        for (int ct = 0; ct < 4; ++ct){
          hh[ct] = *(const short8*)((const char*)sH + swz(base + ct * 256));
          hl[ct] = *(const short8*)((const char*)sH + swz(32768 + base + ct * 256));
        }
        #pragma unroll
        for (int ct = 0; ct < 4; ++ct){
          acc[ct] = __builtin_amdgcn_mfma_f32_16x16x32_bf16(aHiH[kch], hh[ct], acc[ct], 0, 0, 0);
          acc[ct] = __builtin_amdgcn_mfma_f32_16x16x32_bf16(aHiH[kch], hl[ct], acc[ct], 0, 0, 0);
          acc[ct] = __builtin_amdgcn_mfma_f32_16x16x32_bf16(aLoH[kch], hh[ct], acc[ct], 0, 0, 0);
        }
      }
    }

    // ---- F: gate exchange ----
    #pragma unroll
    for (int q = 0; q < 4; ++q){
      const int row = wv * 16 + lg * 4 + q;
      #pragma unroll
      for (int ct = 0; ct < 4; ++ct)
        sGate[row][ct * 16 + lc] = acc[ct][q];
    }
    __syncthreads();

    // ---- G: pointwise update (2 j's per thread), publish h + stage sX ----
    {
      const int a = sAsg[t % 3][ub];
      const int r0 = a * 64 + uj2;
      const float gi0 = sGate[r0][ub],      gi1 = sGate[r0 + 1][ub];
      const float gf0 = sGate[r0 + 16][ub], gf1 = sGate[r0 + 17][ub];
      const float gg0 = sGate[r0 + 32][ub], gg1 = sGate[r0 + 33][ub];
      const float go0 = sGate[r0 + 48][ub], go1 = sGate[r0 + 49][ub];
      const float c0 = (t == 0) ? 0.f : sC[ub][uj2];
      const float c1 = (t == 0) ? 0.f : sC[ub][uj2 + 1];
      const float si0 = 1.f / (1.f + __expf(-gi0)), si1 = 1.f / (1.f + __expf(-gi1));
      const float sf0 = 1.f / (1.f + __expf(-gf0)), sf1 = 1.f / (1.f + __expf(-gf1));
      const float so0 = 1.f / (1.f + __expf(-go0)), so1 = 1.f / (1.f + __expf(-go1));
      const float cn0 = sf0 * c0 + si0 * tanhf(gg0);
      const float cn1 = sf1 * c1 + si1 * tanhf(gg1);
      const float hn0 = so0 * tanhf(cn0);
      const float hn1 = so1 * tanhf(cn1);
      const int j0 = wg * 16 + uj2;
      if (t < SS - 1){
        sC[ub][uj2] = cn0; sC[ub][uj2 + 1] = cn1;
        const unsigned short h0 = f2bf(hn0), h1 = f2bf(hn1);
        const unsigned short l0 = f2bf(hn0 - bf2f(h0)), l1 = f2bf(hn1 - bf2f(h1));
        const unsigned hi2 = (unsigned)h0 | ((unsigned)h1 << 16);
        const unsigned lo2 = (unsigned)l0 | ((unsigned)l1 << 16);
        unsigned short* hw = hbuf + (size_t)((t & 1) ^ 1) * 32768;
        const int off = (((j0 >> 5) * 4 + ((j0 >> 3) & 3)) * 4 + (ub >> 4)) * 128
                        + (ub & 15) * 8 + (j0 & 7);
        unsigned short* pH = hw + off;
        unsigned short* pL = hw + 16384 + off;
        asm volatile("global_store_dword %0, %1, off sc0 sc1" :: "v"(pH), "v"(hi2) : "memory");
        asm volatile("global_store_dword %0, %1, off sc0 sc1" :: "v"(pL), "v"(lo2) : "memory");
      } else {
        out[ub * 512 + j0]           = hn0;
        out[ub * 512 + j0 + 1]       = hn1;
        out[ub * 512 + 256 + j0]     = cn0;
        out[ub * 512 + 256 + j0 + 1] = cn1;
      }
    }
    if (t + 1 < SS){
      #pragma unroll
      for (int ct = 0; ct < 4; ++ct){
        const int byte = ((gkc * 4 + glg) * 4 + ct) * 256 + glc * 16;
        *(short8*)((char*)sX + swz(byte)) = xr[ct];
      }
    }

    // ---- H: release + distributed flag barrier (no fences, no L2 flush) ----
    if (t < SS - 1){
      asm volatile("s_waitcnt vmcnt(0)" ::: "memory");  // h stores ack'd at coherence point
      __syncthreads();
      if (tid == 0){
        const int val = t + 1;
        int* fp = &flags[wg * 16];
        asm volatile("global_store_dword %0, %1, off sc0 sc1" :: "v"(fp), "v"(val) : "memory");
      }
      const int need = t + 1;
      const int* fp2 = &flags[(lane & 15) * 16];
      int fl = need;
      do {
        if (lane < NWG){
          int tmp;
          asm volatile("global_load_dword %0, %1, off sc0 sc1\n\ts_waitcnt vmcnt(0)"
                       : "=v"(tmp) : "v"(fp2) : "memory");
          fl = tmp;
        }
      } while (__ballot(fl < need));
      __builtin_amdgcn_sched_barrier(0);
    }
  }
}

extern "C" void kernel_launch(void* const* d_in, const int* in_sizes, int n_in,
                              void* d_out, int out_size, void* d_ws, size_t ws_size,
                              hipStream_t stream)
{
  const int*   input  = (const int*)  d_in[0];
  const int*   assign = (const int*)  d_in[1];
  const float* emb    = (const float*)d_in[2];
  const float* Wih    = (const float*)d_in[3];
  const float* Whh    = (const float*)d_in[4];
  const float* bih    = (const float*)d_in[5];
  const float* bhh    = (const float*)d_in[6];
  float* out = (float*)d_out;
  char*  ws  = (char*)d_ws;

  zero_flags_kernel<<<1, 256, 0, stream>>>((int*)ws);
  mlstm_kernel<<<NWG, TPB, 0, stream>>>(input, assign, emb, Wih, Whh, bih, bhh, out, ws);
}

// Round 4
// 2856.702 us; speedup vs baseline: 2.2135x; 1.6517x over previous
//
#include <hip/hip_runtime.h>
#include <stdint.h>
#include <stddef.h>

// Routed 2-cell LSTM, B=64, S=512, E=H=256.
// Phase 1 (xproj_kernel, 256 blocks): precompute xg[t][g][b] = routed-cell
//   (W_ih·x_t + b_ih + b_hh) for all t — throughput GEMM, off critical path.
// Phase 2 (mlstm_rec_kernel, 16 persistent wgs): recurrence only —
//   h-MFMAs (split hi/lo bf16), LDS c-state, sc0/sc1 h exchange,
//   single monotonic system-scope step counter.
// Fallback (ws too small): round-3 kernel (x-part in-loop).

#define BB   64
#define SS   512
#define EE   256
#define HH   256
#define G4   1024
#define NWG  16
#define TPB  512
#define TCH  32   // t per xproj chunk

typedef __attribute__((ext_vector_type(8))) short short8;
typedef __attribute__((ext_vector_type(4))) float f32x4;

__device__ __forceinline__ unsigned short f2bf(float f){
  union { float f; unsigned u; } v; v.f = f;
  return (unsigned short)((v.u + 0x7fffu + ((v.u >> 16) & 1u)) >> 16);
}
__device__ __forceinline__ float bf2f(unsigned short s){
  union { float f; unsigned u; } v; v.u = ((unsigned)s) << 16;
  return v.f;
}
__device__ __forceinline__ int swz(int byte){ return byte ^ (((byte >> 10) & 3) << 6); }

// ws: [0,1024) counter+flags; [1024,+131072) h frags (2 parity x 64KB);
//     [132096, +134217728) xg[t=512][g=1024][b=64] fp32
#define WS_H_OFF  1024
#define WS_XG_OFF (1024 + 131072)
#define XG_BYTES  ((size_t)SS * 1024 * 64 * 4)

__global__ void zero_flags_kernel(int* ws){
  if (threadIdx.x < 256) ws[threadIdx.x] = 0;
}

// ---------------- Phase 1: x-projection GEMM ----------------
__global__ __launch_bounds__(TPB, 1)
void xproj_kernel(const int* __restrict__ input, const int* __restrict__ assign,
                  const float* __restrict__ emb, const float* __restrict__ Wih,
                  const float* __restrict__ bih, const float* __restrict__ bhh,
                  float* __restrict__ xg)
{
  __shared__ __align__(16) unsigned short sXp[8][4][4][16][8]; // 32 KB B-frags
  __shared__ int sTokP[TCH][64];
  __shared__ int sAsgP[TCH][64];

  const int tid  = threadIdx.x;
  const int lane = tid & 63;
  const int lg   = lane >> 4;
  const int lc   = lane & 15;
  const int wv   = tid >> 6;
  const int rowtile = blockIdx.x & 15;   // 16 tiles of 128 gate rows (of 2048)
  const int tc      = blockIdx.x >> 4;   // 16 chunks of TCH steps

  const int rbase = rowtile * 128 + wv * 16;   // wave's 16 rows (global, 0..2047)
  const int cellw = rbase >> 10;               // uniform per wave
  const int rrw   = rbase & 1023;

  // A-fragments (hi bf16) of W_ih rows
  short8 aX[8];
  {
    const float* pw = Wih + ((size_t)cellw * G4 + (rrw + lc)) * EE + lg * 8;
    #pragma unroll
    for (int kc = 0; kc < 8; ++kc){
      const f32x4 u = *(const f32x4*)(pw + kc * 32);
      const f32x4 v = *(const f32x4*)(pw + kc * 32 + 4);
      short8 x8;
      #pragma unroll
      for (int e = 0; e < 4; ++e){ x8[e] = (short)f2bf(u[e]); x8[4+e] = (short)f2bf(v[e]); }
      aX[kc] = x8;
    }
  }
  float biasr[4];
  #pragma unroll
  for (int q = 0; q < 4; ++q){
    const int idx = cellw * G4 + rrw + lg * 4 + q;
    biasr[q] = bih[idx] + bhh[idx];
  }

  // stage tokens + routing for the whole chunk
  for (int i = tid; i < TCH * 64; i += TPB){
    const int tl = i >> 6, b = i & 63;
    const int tok = input[b * SS + tc * TCH + tl];
    sTokP[tl][b] = tok; sAsgP[tl][b] = assign[tok];
  }
  __syncthreads();

  const int gkc = tid >> 6, glg = (tid >> 4) & 3, glc = tid & 15;
  short8 xr[4];
  auto GATHERP = [&](int tl){
    #pragma unroll
    for (int ct = 0; ct < 4; ++ct){
      const int tok = sTokP[tl][ct * 16 + glc];
      const float* ep = emb + (size_t)tok * EE + gkc * 32 + glg * 8;
      const f32x4 u = *(const f32x4*)ep;
      const f32x4 v = *(const f32x4*)(ep + 4);
      short8 x8;
      #pragma unroll
      for (int e = 0; e < 4; ++e){ x8[e] = (short)f2bf(u[e]); x8[4+e] = (short)f2bf(v[e]); }
      xr[ct] = x8;
    }
  };
  GATHERP(0);

  for (int tl = 0; tl < TCH; ++tl){
    #pragma unroll
    for (int ct = 0; ct < 4; ++ct)
      *(short8*)&sXp[gkc][glg][ct][glc][0] = xr[ct];
    __syncthreads();
    if (tl + 1 < TCH) GATHERP(tl + 1);

    f32x4 acc[4];
    #pragma unroll
    for (int ct = 0; ct < 4; ++ct){
      acc[ct][0] = biasr[0]; acc[ct][1] = biasr[1];
      acc[ct][2] = biasr[2]; acc[ct][3] = biasr[3];
    }
    #pragma unroll
    for (int kc = 0; kc < 8; ++kc){
      #pragma unroll
      for (int ct = 0; ct < 4; ++ct){
        const short8 bx = *(const short8*)&sXp[kc][lg][ct][lc][0];
        acc[ct] = __builtin_amdgcn_mfma_f32_16x16x32_bf16(aX[kc], bx, acc[ct], 0, 0, 0);
      }
    }
    // routed select + store
    float* xgt = xg + (size_t)(tc * TCH + tl) * 65536;
    #pragma unroll
    for (int ct = 0; ct < 4; ++ct){
      const int b = ct * 16 + lc;
      if (sAsgP[tl][b] == cellw){
        #pragma unroll
        for (int q = 0; q < 4; ++q)
          xgt[(rrw + lg * 4 + q) * 64 + b] = acc[ct][q];
      }
    }
    __syncthreads();
  }
}

// ---------------- Phase 2: recurrence ----------------
__global__ __launch_bounds__(TPB, 1)
void mlstm_rec_kernel(const int* __restrict__ input, const int* __restrict__ assign,
                      const float* __restrict__ Whh, float* __restrict__ out,
                      char* __restrict__ ws)
{
  __shared__ __align__(16) unsigned short sH[32768];  // 64 KB staged h (hi|lo), swizzled
  __shared__ float sGate[128][66];
  __shared__ float sC[64][16];
  __shared__ int sAsg[3][64];

  const int tid  = threadIdx.x;
  const int lane = tid & 63;
  const int lg   = lane >> 4;
  const int lc   = lane & 15;
  const int wv   = tid >> 6;
  const int wg   = blockIdx.x;
  const int cell = wv >> 2;
  const int gate = wv & 3;

  int* cnt = (int*)ws;
  unsigned short* hbuf = (unsigned short*)(ws + WS_H_OFF);
  const float* xg = (const float*)(ws + WS_XG_OFF);

  // Whh A-frags hi/lo (register-resident)
  short8 aHiH[8], aLoH[8];
  {
    const float* ph = Whh + ((size_t)cell * G4 + gate * HH + wg * 16 + lc) * HH + lg * 8;
    #pragma unroll
    for (int kc = 0; kc < 8; ++kc){
      const f32x4 u = *(const f32x4*)(ph + kc * 32);
      const f32x4 v = *(const f32x4*)(ph + kc * 32 + 4);
      short8 hi, lo;
      #pragma unroll
      for (int e = 0; e < 4; ++e){
        const float w0 = u[e], w1 = v[e];
        const unsigned short h0 = f2bf(w0), h1 = f2bf(w1);
        hi[e] = (short)h0;   lo[e] = (short)f2bf(w0 - bf2f(h0));
        hi[4+e] = (short)h1; lo[4+e] = (short)f2bf(w1 - bf2f(h1));
      }
      aHiH[kc] = hi; aLoH[kc] = lo;
    }
  }

  if (tid < 64){
    const int t0 = input[tid * SS];     sAsg[0][tid] = assign[t0];
    const int t1 = input[tid * SS + 1]; sAsg[1][tid] = assign[t1];
  }

  // xg acc-init prefetch (one step ahead, 16 VGPRs)
  float xpre[16];
  const int xrow = gate * HH + wg * 16 + lg * 4;   // + q
  auto XPRE = [&](int t){
    const float* p = xg + (size_t)t * 65536 + xrow * 64 + lc;
    #pragma unroll
    for (int ct = 0; ct < 4; ++ct)
      #pragma unroll
      for (int q = 0; q < 4; ++q)
        xpre[ct * 4 + q] = p[q * 64 + ct * 16];
  };
  XPRE(0);
  __syncthreads();

  const int ub  = tid >> 3;
  const int uj2 = (tid & 7) * 2;

  for (int t = 0; t < SS; ++t){
    // ---- poll step counter, then load + stage h ----
    if (t > 0){
      const int tgt = NWG * t;
      int v;
      do {
        asm volatile("global_load_dword %0, %1, off sc0 sc1\n\ts_waitcnt vmcnt(0)"
                     : "=v"(v) : "v"(cnt) : "memory");
        if (v < tgt) __builtin_amdgcn_s_sleep(1);
      } while (v < tgt);

      const unsigned short* hr = hbuf + (size_t)(t & 1) * 32768;
      short8 hcp[8];
      #pragma unroll
      for (int i = 0; i < 8; ++i){
        const unsigned short* p = hr + (i * 512 + tid) * 8;
        asm volatile("global_load_dwordx4 %0, %1, off sc0 sc1"
                     : "=v"(hcp[i]) : "v"(p) : "memory");
      }
      asm volatile("s_waitcnt vmcnt(0)" ::: "memory");
      __builtin_amdgcn_sched_barrier(0);
      #pragma unroll
      for (int i = 0; i < 8; ++i)
        *(short8*)((char*)sH + swz((i * 512 + tid) * 16)) = hcp[i];
      __syncthreads();
    }

    // ---- acc init from precomputed x-projection ----
    f32x4 acc[4];
    #pragma unroll
    for (int ct = 0; ct < 4; ++ct)
      #pragma unroll
      for (int q = 0; q < 4; ++q)
        acc[ct][q] = xpre[ct * 4 + q];
    if (t + 1 < SS) XPRE(t + 1);                      // prefetch next step
    if (t + 2 < SS && tid < 64){                      // routing prefetch
      const int tk = input[tid * SS + (t + 2)];
      sAsg[(t + 2) % 3][tid] = assign[tk];
    }

    // ---- h-part MFMAs ----
    if (t > 0){
      #pragma unroll
      for (int kch = 0; kch < 8; ++kch){
        const int base = (kch * 4 + lg) * 1024 + lc * 16;
        short8 hh[4], hl[4];
        #pragma unroll
        for (int ct = 0; ct < 4; ++ct){
          hh[ct] = *(const short8*)((const char*)sH + swz(base + ct * 256));
          hl[ct] = *(const short8*)((const char*)sH + swz(32768 + base + ct * 256));
        }
        #pragma unroll
        for (int ct = 0; ct < 4; ++ct){
          acc[ct] = __builtin_amdgcn_mfma_f32_16x16x32_bf16(aHiH[kch], hh[ct], acc[ct], 0, 0, 0);
          acc[ct] = __builtin_amdgcn_mfma_f32_16x16x32_bf16(aHiH[kch], hl[ct], acc[ct], 0, 0, 0);
          acc[ct] = __builtin_amdgcn_mfma_f32_16x16x32_bf16(aLoH[kch], hh[ct], acc[ct], 0, 0, 0);
        }
      }
    }

    // ---- gate exchange ----
    #pragma unroll
    for (int q = 0; q < 4; ++q){
      const int row = wv * 16 + lg * 4 + q;
      #pragma unroll
      for (int ct = 0; ct < 4; ++ct)
        sGate[row][ct * 16 + lc] = acc[ct][q];
    }
    __syncthreads();

    // ---- pointwise update, publish h ----
    {
      const int a = sAsg[t % 3][ub];
      const int r0 = a * 64 + uj2;
      const float gi0 = sGate[r0][ub],      gi1 = sGate[r0 + 1][ub];
      const float gf0 = sGate[r0 + 16][ub], gf1 = sGate[r0 + 17][ub];
      const float gg0 = sGate[r0 + 32][ub], gg1 = sGate[r0 + 33][ub];
      const float go0 = sGate[r0 + 48][ub], go1 = sGate[r0 + 49][ub];
      const float c0 = (t == 0) ? 0.f : sC[ub][uj2];
      const float c1 = (t == 0) ? 0.f : sC[ub][uj2 + 1];
      const float si0 = 1.f / (1.f + __expf(-gi0)), si1 = 1.f / (1.f + __expf(-gi1));
      const float sf0 = 1.f / (1.f + __expf(-gf0)), sf1 = 1.f / (1.f + __expf(-gf1));
      const float so0 = 1.f / (1.f + __expf(-go0)), so1 = 1.f / (1.f + __expf(-go1));
      const float cn0 = sf0 * c0 + si0 * tanhf(gg0);
      const float cn1 = sf1 * c1 + si1 * tanhf(gg1);
      const float hn0 = so0 * tanhf(cn0);
      const float hn1 = so1 * tanhf(cn1);
      const int j0 = wg * 16 + uj2;
      if (t < SS - 1){
        sC[ub][uj2] = cn0; sC[ub][uj2 + 1] = cn1;
        const unsigned short h0 = f2bf(hn0), h1 = f2bf(hn1);
        const unsigned short l0 = f2bf(hn0 - bf2f(h0)), l1 = f2bf(hn1 - bf2f(h1));
        const unsigned hi2 = (unsigned)h0 | ((unsigned)h1 << 16);
        const unsigned lo2 = (unsigned)l0 | ((unsigned)l1 << 16);
        unsigned short* hw = hbuf + (size_t)((t & 1) ^ 1) * 32768;
        const int off = (((j0 >> 5) * 4 + ((j0 >> 3) & 3)) * 4 + (ub >> 4)) * 128
                        + (ub & 15) * 8 + (j0 & 7);
        unsigned short* pH = hw + off;
        unsigned short* pL = hw + 16384 + off;
        asm volatile("global_store_dword %0, %1, off sc0 sc1" :: "v"(pH), "v"(hi2) : "memory");
        asm volatile("global_store_dword %0, %1, off sc0 sc1" :: "v"(pL), "v"(lo2) : "memory");
      } else {
        out[ub * 512 + j0]           = hn0;
        out[ub * 512 + j0 + 1]       = hn1;
        out[ub * 512 + 256 + j0]     = cn0;
        out[ub * 512 + 256 + j0 + 1] = cn1;
      }
    }

    // ---- release + bump step counter ----
    if (t < SS - 1){
      asm volatile("s_waitcnt vmcnt(0)" ::: "memory");
      __syncthreads();
      if (tid == 0)
        __hip_atomic_fetch_add(cnt, 1, __ATOMIC_RELAXED, __HIP_MEMORY_SCOPE_SYSTEM);
      __syncthreads();
    }
  }
}

// ---------------- Fallback (round-3 kernel, in-loop x-part) ----------------
__global__ __launch_bounds__(TPB, 2)
void mlstm_kernel(const int* __restrict__ input, const int* __restrict__ assign,
                  const float* __restrict__ emb, const float* __restrict__ Wih,
                  const float* __restrict__ Whh, const float* __restrict__ bih,
                  const float* __restrict__ bhh, float* __restrict__ out,
                  char* __restrict__ ws)
{
  __shared__ __align__(16) unsigned short sH[32768];
  __shared__ __align__(16) unsigned short sX[16384];
  __shared__ float sGate[128][66];
  __shared__ float sC[64][16];
  __shared__ int sTok[3][64];
  __shared__ int sAsg[3][64];

  const int tid  = threadIdx.x;
  const int lane = tid & 63;
  const int lg   = lane >> 4;
  const int lc   = lane & 15;
  const int wv   = tid >> 6;
  const int wg   = blockIdx.x;
  const int cell = wv >> 2;
  const int gate = wv & 3;

  int* flags = (int*)ws;
  unsigned short* hbuf = (unsigned short*)(ws + WS_H_OFF);

  const size_t rowA = (size_t)cell * G4 + (size_t)gate * HH + wg * 16 + lc;
  short8 aHiH[8], aLoH[8], aHiX[8];
  {
    const float* ph = Whh + rowA * HH + lg * 8;
    const float* px = Wih + rowA * EE + lg * 8;
    #pragma unroll
    for (int kc = 0; kc < 8; ++kc){
      const f32x4 u = *(const f32x4*)(ph + kc * 32);
      const f32x4 v = *(const f32x4*)(ph + kc * 32 + 4);
      short8 hi, lo;
      #pragma unroll
      for (int e = 0; e < 4; ++e){
        const float w0 = u[e], w1 = v[e];
        const unsigned short h0 = f2bf(w0), h1 = f2bf(w1);
        hi[e] = (short)h0;   lo[e] = (short)f2bf(w0 - bf2f(h0));
        hi[4+e] = (short)h1; lo[4+e] = (short)f2bf(w1 - bf2f(h1));
      }
      aHiH[kc] = hi; aLoH[kc] = lo;
      const f32x4 a = *(const f32x4*)(px + kc * 32);
      const f32x4 b = *(const f32x4*)(px + kc * 32 + 4);
      short8 xh;
      #pragma unroll
      for (int e = 0; e < 4; ++e){ xh[e] = (short)f2bf(a[e]); xh[4+e] = (short)f2bf(b[e]); }
      aHiX[kc] = xh;
    }
  }
  float biasr[4];
  #pragma unroll
  for (int q = 0; q < 4; ++q){
    const int idx = cell * G4 + gate * HH + wg * 16 + lg * 4 + q;
    biasr[q] = bih[idx] + bhh[idx];
  }

  const int gkc = tid >> 6, glg = (tid >> 4) & 3, glc = tid & 15;
  const int ub  = tid >> 3;
  const int uj2 = (tid & 7) * 2;

  if (tid < 64){
    const int t0 = input[tid * SS];     sTok[0][tid] = t0; sAsg[0][tid] = assign[t0];
    const int t1 = input[tid * SS + 1]; sTok[1][tid] = t1; sAsg[1][tid] = assign[t1];
  }
  __syncthreads();
  {
    #pragma unroll
    for (int ct = 0; ct < 4; ++ct){
      const int tok = sTok[0][ct * 16 + glc];
      const float* ep = emb + (size_t)tok * EE + gkc * 32 + glg * 8;
      const f32x4 u = *(const f32x4*)ep;
      const f32x4 v = *(const f32x4*)(ep + 4);
      short8 x8;
      #pragma unroll
      for (int e = 0; e < 4; ++e){ x8[e] = (short)f2bf(u[e]); x8[4+e] = (short)f2bf(v[e]); }
      const int byte = ((gkc * 4 + glg) * 4 + ct) * 256 + glc * 16;
      *(short8*)((char*)sX + swz(byte)) = x8;
    }
  }
  __syncthreads();

  for (int t = 0; t < SS; ++t){
    const int s1 = (t + 1) % 3, s2 = (t + 2) % 3;

    short8 hcp[8];
    if (t > 0){
      const unsigned short* hr = hbuf + (size_t)(t & 1) * 32768;
      #pragma unroll
      for (int i = 0; i < 8; ++i){
        const unsigned short* p = hr + (i * 512 + tid) * 8;
        asm volatile("global_load_dwordx4 %0, %1, off sc0 sc1"
                     : "=v"(hcp[i]) : "v"(p) : "memory");
      }
    }

    f32x4 acc[4];
    #pragma unroll
    for (int ct = 0; ct < 4; ++ct){
      acc[ct][0] = biasr[0]; acc[ct][1] = biasr[1];
      acc[ct][2] = biasr[2]; acc[ct][3] = biasr[3];
    }
    #pragma unroll
    for (int kc = 0; kc < 8; ++kc){
      const int bb = (kc * 4 + lg) * 1024 + lc * 16;
      #pragma unroll
      for (int ct = 0; ct < 4; ++ct){
        const short8 bx = *(const short8*)((const char*)sX + swz(bb + ct * 256));
        acc[ct] = __builtin_amdgcn_mfma_f32_16x16x32_bf16(aHiX[kc], bx, acc[ct], 0, 0, 0);
      }
    }

    if (t > 0){
      asm volatile("s_waitcnt vmcnt(0)" ::: "memory");
      __builtin_amdgcn_sched_barrier(0);
      #pragma unroll
      for (int i = 0; i < 8; ++i)
        *(short8*)((char*)sH + swz((i * 512 + tid) * 16)) = hcp[i];
      __syncthreads();
    }

    short8 xr[4];
    if (t + 1 < SS){
      if (tid < 64 && t + 2 < SS){
        const int tk = input[tid * SS + (t + 2)];
        sTok[s2][tid] = tk; sAsg[s2][tid] = assign[tk];
      }
      #pragma unroll
      for (int ct = 0; ct < 4; ++ct){
        const int tok = sTok[s1][ct * 16 + glc];
        const float* ep = emb + (size_t)tok * EE + gkc * 32 + glg * 8;
        const f32x4 u = *(const f32x4*)ep;
        const f32x4 v = *(const f32x4*)(ep + 4);
        short8 x8;
        #pragma unroll
        for (int e = 0; e < 4; ++e){ x8[e] = (short)f2bf(u[e]); x8[4+e] = (short)f2bf(v[e]); }
        xr[ct] = x8;
      }
    }

    if (t > 0){
      #pragma unroll
      for (int kch = 0; kch < 8; ++kch){
        const int base = (kch * 4 + lg) * 1024 + lc * 16;
        short8 hh[4], hl[4];
        #pragma unroll
        for (int ct = 0; ct < 4; ++ct){
          hh[ct] = *(const short8*)((const char*)sH + swz(base + ct * 256));
          hl[ct] = *(const short8*)((const char*)sH + swz(32768 + base + ct * 256));
        }
        #pragma unroll
        for (int ct = 0; ct < 4; ++ct){
          acc[ct] = __builtin_amdgcn_mfma_f32_16x16x32_bf16(aHiH[kch], hh[ct], acc[ct], 0, 0, 0);
          acc[ct] = __builtin_amdgcn_mfma_f32_16x16x32_bf16(aHiH[kch], hl[ct], acc[ct], 0, 0, 0);
          acc[ct] = __builtin_amdgcn_mfma_f32_16x16x32_bf16(aLoH[kch], hh[ct], acc[ct], 0, 0, 0);
        }
      }
    }

    #pragma unroll
    for (int q = 0; q < 4; ++q){
      const int row = wv * 16 + lg * 4 + q;
      #pragma unroll
      for (int ct = 0; ct < 4; ++ct)
        sGate[row][ct * 16 + lc] = acc[ct][q];
    }
    __syncthreads();

    {
      const int a = sAsg[t % 3][ub];
      const int r0 = a * 64 + uj2;
      const float gi0 = sGate[r0][ub],      gi1 = sGate[r0 + 1][ub];
      const float gf0 = sGate[r0 + 16][ub], gf1 = sGate[r0 + 17][ub];
      const float gg0 = sGate[r0 + 32][ub], gg1 = sGate[r0 + 33][ub];
      const float go0 = sGate[r0 + 48][ub], go1 = sGate[r0 + 49][ub];
      const float c0 = (t == 0) ? 0.f : sC[ub][uj2];
      const float c1 = (t == 0) ? 0.f : sC[ub][uj2 + 1];
      const float si0 = 1.f / (1.f + __expf(-gi0)), si1 = 1.f / (1.f + __expf(-gi1));
      const float sf0 = 1.f / (1.f + __expf(-gf0)), sf1 = 1.f / (1.f + __expf(-gf1));
      const float so0 = 1.f / (1.f + __expf(-go0)), so1 = 1.f / (1.f + __expf(-go1));
      const float cn0 = sf0 * c0 + si0 * tanhf(gg0);
      const float cn1 = sf1 * c1 + si1 * tanhf(gg1);
      const float hn0 = so0 * tanhf(cn0);
      const float hn1 = so1 * tanhf(cn1);
      const int j0 = wg * 16 + uj2;
      if (t < SS - 1){
        sC[ub][uj2] = cn0; sC[ub][uj2 + 1] = cn1;
        const unsigned short h0 = f2bf(hn0), h1 = f2bf(hn1);
        const unsigned short l0 = f2bf(hn0 - bf2f(h0)), l1 = f2bf(hn1 - bf2f(h1));
        const unsigned hi2 = (unsigned)h0 | ((unsigned)h1 << 16);
        const unsigned lo2 = (unsigned)l0 | ((unsigned)l1 << 16);
        unsigned short* hw = hbuf + (size_t)((t & 1) ^ 1) * 32768;
        const int off = (((j0 >> 5) * 4 + ((j0 >> 3) & 3)) * 4 + (ub >> 4)) * 128
                        + (ub & 15) * 8 + (j0 & 7);
        unsigned short* pH = hw + off;
        unsigned short* pL = hw + 16384 + off;
        asm volatile("global_store_dword %0, %1, off sc0 sc1" :: "v"(pH), "v"(hi2) : "memory");
        asm volatile("global_store_dword %0, %1, off sc0 sc1" :: "v"(pL), "v"(lo2) : "memory");
      } else {
        out[ub * 512 + j0]           = hn0;
        out[ub * 512 + j0 + 1]       = hn1;
        out[ub * 512 + 256 + j0]     = cn0;
        out[ub * 512 + 256 + j0 + 1] = cn1;
      }
    }
    if (t + 1 < SS){
      #pragma unroll
      for (int ct = 0; ct < 4; ++ct){
        const int byte = ((gkc * 4 + glg) * 4 + ct) * 256 + glc * 16;
        *(short8*)((char*)sX + swz(byte)) = xr[ct];
      }
    }

    if (t < SS - 1){
      asm volatile("s_waitcnt vmcnt(0)" ::: "memory");
      __syncthreads();
      if (tid == 0){
        const int val = t + 1;
        int* fp = &flags[wg * 16];
        asm volatile("global_store_dword %0, %1, off sc0 sc1" :: "v"(fp), "v"(val) : "memory");
      }
      const int need = t + 1;
      const int* fp2 = &flags[(lane & 15) * 16];
      int fl = need;
      do {
        if (lane < NWG){
          int tmp;
          asm volatile("global_load_dword %0, %1, off sc0 sc1\n\ts_waitcnt vmcnt(0)"
                       : "=v"(tmp) : "v"(fp2) : "memory");
          fl = tmp;
        }
      } while (__ballot(fl < need));
      __builtin_amdgcn_sched_barrier(0);
    }
  }
}

extern "C" void kernel_launch(void* const* d_in, const int* in_sizes, int n_in,
                              void* d_out, int out_size, void* d_ws, size_t ws_size,
                              hipStream_t stream)
{
  const int*   input  = (const int*)  d_in[0];
  const int*   assign = (const int*)  d_in[1];
  const float* emb    = (const float*)d_in[2];
  const float* Wih    = (const float*)d_in[3];
  const float* Whh    = (const float*)d_in[4];
  const float* bih    = (const float*)d_in[5];
  const float* bhh    = (const float*)d_in[6];
  float* out = (float*)d_out;
  char*  ws  = (char*)d_ws;

  zero_flags_kernel<<<1, 256, 0, stream>>>((int*)ws);

  const size_t need = (size_t)WS_XG_OFF + XG_BYTES;
  if (ws_size >= need){
    float* xg = (float*)(ws + WS_XG_OFF);
    xproj_kernel<<<256, TPB, 0, stream>>>(input, assign, emb, Wih, bih, bhh, xg);
    mlstm_rec_kernel<<<NWG, TPB, 0, stream>>>(input, assign, Whh, out, ws);
  } else {
    mlstm_kernel<<<NWG, TPB, 0, stream>>>(input, assign, emb, Wih, Whh, bih, bhh, out, ws);
  }
}

// Round 6
// 2362.317 us; speedup vs baseline: 2.6768x; 1.2093x over previous
//
#include <hip/hip_runtime.h>
#include <stdint.h>
#include <stddef.h>

// Routed 2-cell LSTM, B=64, S=512, E=H=256.
// Phase 1 (xproj_kernel, 256 blocks): precompute xg[t][g][b] = routed-cell
//   (W_ih·x_t + b_ih + b_hh) for all t — throughput GEMM, off critical path.
// Phase 2 (mlstm_rec_kernel, 32 persistent wgs, anywhere on the device):
//   wg owns 8 hidden units for BOTH cells (64 gate rows). Per step: stage all
//   of h (hi/lo bf16) from IF-coherent scratch into LDS, 48 MFMAs/wave,
//   routed pointwise update, publish h slice. Sync = 32 per-wg flag words,
//   all sc0 sc1 (Infinity-Cache coherence point) — parallel stores + polls,
//   NO atomics/RMW in the serial loop (round-4's serialized counter removed).

#define BB   64
#define SS   512
#define EE   256
#define HH   256
#define G4   1024
#define NWG  32
#define TPB  512
#define TCH  32    // t per xproj chunk

typedef __attribute__((ext_vector_type(8))) short short8;
typedef __attribute__((ext_vector_type(4))) float f32x4;

__device__ __forceinline__ unsigned short f2bf(float f){
  union { float f; unsigned u; } v; v.f = f;
  return (unsigned short)((v.u + 0x7fffu + ((v.u >> 16) & 1u)) >> 16);
}
__device__ __forceinline__ float bf2f(unsigned short s){
  union { float f; unsigned u; } v; v.u = ((unsigned)s) << 16;
  return v.f;
}
__device__ __forceinline__ int swz(int byte){ return byte ^ (((byte >> 10) & 3) << 6); }

// ws layout (bytes):
// [0,128)              : flags[32]
// [1024, +131072)      : h frags, 2 parities x 64KB (hi 32KB | lo 32KB each)
// [132096, +134217728) : xg[t=512][g=1024][b=64] fp32 (routed-cell gates)
#define WS_H_OFF  1024
#define WS_XG_OFF (1024 + 131072)

__global__ void zero_flags_kernel(int* ws){
  if (threadIdx.x < 256) ws[threadIdx.x] = 0;
}

// ---------------- Phase 1: x-projection GEMM ----------------
__global__ __launch_bounds__(TPB, 1)
void xproj_kernel(const int* __restrict__ input, const int* __restrict__ assign,
                  const float* __restrict__ emb, const float* __restrict__ Wih,
                  const float* __restrict__ bih, const float* __restrict__ bhh,
                  float* __restrict__ xg)
{
  __shared__ __align__(16) unsigned short sXp[8][4][4][16][8];
  __shared__ int sTokP[TCH][64];
  __shared__ int sAsgP[TCH][64];

  const int tid  = threadIdx.x;
  const int lane = tid & 63;
  const int lg   = lane >> 4;
  const int lc   = lane & 15;
  const int wv   = tid >> 6;
  const int rowtile = blockIdx.x & 15;
  const int tc      = blockIdx.x >> 4;

  const int rbase = rowtile * 128 + wv * 16;
  const int cellw = rbase >> 10;
  const int rrw   = rbase & 1023;

  short8 aX[8];
  {
    const float* pw = Wih + ((size_t)cellw * G4 + (rrw + lc)) * EE + lg * 8;
    #pragma unroll
    for (int kc = 0; kc < 8; ++kc){
      const f32x4 u = *(const f32x4*)(pw + kc * 32);
      const f32x4 v = *(const f32x4*)(pw + kc * 32 + 4);
      short8 x8;
      #pragma unroll
      for (int e = 0; e < 4; ++e){ x8[e] = (short)f2bf(u[e]); x8[4+e] = (short)f2bf(v[e]); }
      aX[kc] = x8;
    }
  }
  float biasr[4];
  #pragma unroll
  for (int q = 0; q < 4; ++q){
    const int idx = cellw * G4 + rrw + lg * 4 + q;
    biasr[q] = bih[idx] + bhh[idx];
  }

  for (int i = tid; i < TCH * 64; i += TPB){
    const int tl = i >> 6, b = i & 63;
    const int tok = input[b * SS + tc * TCH + tl];
    sTokP[tl][b] = tok; sAsgP[tl][b] = assign[tok];
  }
  __syncthreads();

  const int gkc = tid >> 6, glg = (tid >> 4) & 3, glc = tid & 15;
  short8 xr[4];
  auto GATHERP = [&](int tl){
    #pragma unroll
    for (int ct = 0; ct < 4; ++ct){
      const int tok = sTokP[tl][ct * 16 + glc];
      const float* ep = emb + (size_t)tok * EE + gkc * 32 + glg * 8;
      const f32x4 u = *(const f32x4*)ep;
      const f32x4 v = *(const f32x4*)(ep + 4);
      short8 x8;
      #pragma unroll
      for (int e = 0; e < 4; ++e){ x8[e] = (short)f2bf(u[e]); x8[4+e] = (short)f2bf(v[e]); }
      xr[ct] = x8;
    }
  };
  GATHERP(0);

  for (int tl = 0; tl < TCH; ++tl){
    #pragma unroll
    for (int ct = 0; ct < 4; ++ct)
      *(short8*)&sXp[gkc][glg][ct][glc][0] = xr[ct];
    __syncthreads();
    if (tl + 1 < TCH) GATHERP(tl + 1);

    f32x4 acc[4];
    #pragma unroll
    for (int ct = 0; ct < 4; ++ct){
      acc[ct][0] = biasr[0]; acc[ct][1] = biasr[1];
      acc[ct][2] = biasr[2]; acc[ct][3] = biasr[3];
    }
    #pragma unroll
    for (int kc = 0; kc < 8; ++kc){
      #pragma unroll
      for (int ct = 0; ct < 4; ++ct){
        const short8 bx = *(const short8*)&sXp[kc][lg][ct][lc][0];
        acc[ct] = __builtin_amdgcn_mfma_f32_16x16x32_bf16(aX[kc], bx, acc[ct], 0, 0, 0);
      }
    }
    float* xgt = xg + (size_t)(tc * TCH + tl) * 65536;
    #pragma unroll
    for (int ct = 0; ct < 4; ++ct){
      const int b = ct * 16 + lc;
      if (sAsgP[tl][b] == cellw){
        #pragma unroll
        for (int q = 0; q < 4; ++q)
          xgt[(rrw + lg * 4 + q) * 64 + b] = acc[ct][q];
      }
    }
    __syncthreads();
  }
}

// ---------------- Phase 2: recurrence (32 wgs, IF-scope exchange) ----------------
__global__ __launch_bounds__(TPB, 1)
void mlstm_rec_kernel(const int* __restrict__ input, const int* __restrict__ assign,
                      const float* __restrict__ Whh, float* __restrict__ out,
                      char* __restrict__ ws)
{
  __shared__ __align__(16) unsigned short sH[32768];  // 64 KB staged h (hi|lo), swizzled
  __shared__ float sGate[64][66];                     // 16.9 KB
  __shared__ float sC[64][8];                         // 2 KB
  __shared__ int sAsg[3][64];

  const int tid  = threadIdx.x;
  const int lane = tid & 63;
  const int lg   = lane >> 4;
  const int lc   = lane & 15;
  const int wv   = tid >> 6;       // 0..7
  const int rt   = wv & 3;         // row-tile 0..3: cell=rt>>1, gate-pair=rt&1
  const int th   = wv >> 2;        // token half 0..1 (tiles th*2, th*2+1)
  const int wg   = blockIdx.x;     // 0..31: owns j in [wg*8, wg*8+8)
  const int cell = rt >> 1;
  const int gp   = rt & 1;

  int* flags = (int*)ws;
  unsigned short* hbuf = (unsigned short*)(ws + WS_H_OFF);
  const float* xg = (const float*)(ws + WS_XG_OFF);

  // ---- Whh A-frags hi/lo (register-resident) ----
  // A-row m=lc -> gate = gp*2 + (lc>>3), jl = lc&7
  short8 aHiH[8], aLoH[8];
  {
    const float* ph = Whh + ((size_t)cell * G4 + (gp * 2 + (lc >> 3)) * HH + wg * 8 + (lc & 7)) * HH + lg * 8;
    #pragma unroll
    for (int kc = 0; kc < 8; ++kc){
      const f32x4 u = *(const f32x4*)(ph + kc * 32);
      const f32x4 v = *(const f32x4*)(ph + kc * 32 + 4);
      short8 hi, lo;
      #pragma unroll
      for (int e = 0; e < 4; ++e){
        const float w0 = u[e], w1 = v[e];
        const unsigned short h0 = f2bf(w0), h1 = f2bf(w1);
        hi[e] = (short)h0;   lo[e] = (short)f2bf(w0 - bf2f(h0));
        hi[4+e] = (short)h1; lo[4+e] = (short)f2bf(w1 - bf2f(h1));
      }
      aHiH[kc] = hi; aLoH[kc] = lo;
    }
  }

  if (tid < 64){
    const int t0 = input[tid * SS];     sAsg[0][tid] = assign[t0];
    const int t1 = input[tid * SS + 1]; sAsg[1][tid] = assign[t1];
  }

  // xg acc-init prefetch: lane's row base (gate fixed per (rt,lg)):
  // rr = lg*4+q -> gate = gp*2 + (lg>>1), jl = (lg&1)*4 + q
  float xpre[8];                       // [i=token tile 0..1][q]
  const int xrow = (gp * 2 + (lg >> 1)) * HH + wg * 8 + (lg & 1) * 4;
  auto XPRE = [&](int t){
    const float* p = xg + (size_t)t * 65536 + xrow * 64 + th * 32 + lc;
    #pragma unroll
    for (int i = 0; i < 2; ++i)
      #pragma unroll
      for (int q = 0; q < 4; ++q)
        xpre[i * 4 + q] = p[q * 64 + i * 16];
  };
  XPRE(0);
  __syncthreads();

  const int ub = tid >> 3;     // update batch 0..63
  const int uj = tid & 7;      // update j-local 0..7

  for (int t = 0; t < SS; ++t){
    // ---- wait for all 32 flags >= t (parallel poll, sc0 sc1) ----
    if (t > 0){
      const int need = t;
      const int* fp2 = &flags[lane & 31];
      int fl = need;
      do {
        if (lane < NWG){
          int tmp;
          asm volatile("global_load_dword %0, %1, off sc0 sc1\n\ts_waitcnt vmcnt(0)"
                       : "=v"(tmp) : "v"(fp2) : "memory");
          fl = tmp;
          if (tmp < need) __builtin_amdgcn_s_sleep(1);
        }
      } while (__ballot(fl < need));

      // ---- load + stage h ----
      const unsigned short* hr = hbuf + (size_t)(t & 1) * 32768;
      short8 hcp[8];
      #pragma unroll
      for (int i = 0; i < 8; ++i){
        const unsigned short* p = hr + (i * 512 + tid) * 8;
        asm volatile("global_load_dwordx4 %0, %1, off sc0 sc1"
                     : "=v"(hcp[i]) : "v"(p) : "memory");
      }
      asm volatile("s_waitcnt vmcnt(0)" ::: "memory");
      __builtin_amdgcn_sched_barrier(0);
      #pragma unroll
      for (int i = 0; i < 8; ++i)
        *(short8*)((char*)sH + swz((i * 512 + tid) * 16)) = hcp[i];
      __syncthreads();
    }

    // ---- acc init from xg; prefetch next step + routing ----
    f32x4 acc[2];
    #pragma unroll
    for (int i = 0; i < 2; ++i)
      #pragma unroll
      for (int q = 0; q < 4; ++q)
        acc[i][q] = xpre[i * 4 + q];
    if (t + 1 < SS) XPRE(t + 1);
    if (t + 2 < SS && tid < 64){
      const int tk = input[tid * SS + (t + 2)];
      sAsg[(t + 2) % 3][tid] = assign[tk];
    }

    // ---- h-part MFMAs (48/wave) ----
    if (t > 0){
      #pragma unroll
      for (int kch = 0; kch < 8; ++kch){
        const int base = (kch * 4 + lg) * 1024 + lc * 16 + th * 512;
        const short8 hh0 = *(const short8*)((const char*)sH + swz(base));
        const short8 hh1 = *(const short8*)((const char*)sH + swz(base + 256));
        const short8 hl0 = *(const short8*)((const char*)sH + swz(32768 + base));
        const short8 hl1 = *(const short8*)((const char*)sH + swz(32768 + base + 256));
        acc[0] = __builtin_amdgcn_mfma_f32_16x16x32_bf16(aHiH[kch], hh0, acc[0], 0, 0, 0);
        acc[1] = __builtin_amdgcn_mfma_f32_16x16x32_bf16(aHiH[kch], hh1, acc[1], 0, 0, 0);
        acc[0] = __builtin_amdgcn_mfma_f32_16x16x32_bf16(aHiH[kch], hl0, acc[0], 0, 0, 0);
        acc[1] = __builtin_amdgcn_mfma_f32_16x16x32_bf16(aHiH[kch], hl1, acc[1], 0, 0, 0);
        acc[0] = __builtin_amdgcn_mfma_f32_16x16x32_bf16(aLoH[kch], hh0, acc[0], 0, 0, 0);
        acc[1] = __builtin_amdgcn_mfma_f32_16x16x32_bf16(aLoH[kch], hh1, acc[1], 0, 0, 0);
      }
    }

    // ---- gate exchange: rows rt*16+lg*4+q = cell*32+gate*8+jl ----
    #pragma unroll
    for (int q = 0; q < 4; ++q){
      const int row = rt * 16 + lg * 4 + q;
      sGate[row][(th * 2) * 16 + lc] = acc[0][q];
      sGate[row][(th * 2 + 1) * 16 + lc] = acc[1][q];
    }
    __syncthreads();

    // ---- pointwise update (1 (b,j) per thread), publish h ----
    {
      const int a = sAsg[t % 3][ub];
      const int r0 = a * 32 + uj;
      const float gi = sGate[r0][ub];
      const float gf = sGate[r0 + 8][ub];
      const float gg = sGate[r0 + 16][ub];
      const float go = sGate[r0 + 24][ub];
      const float cold = (t == 0) ? 0.f : sC[ub][uj];
      const float si = 1.f / (1.f + __expf(-gi));
      const float sf = 1.f / (1.f + __expf(-gf));
      const float so = 1.f / (1.f + __expf(-go));
      const float cn = sf * cold + si * tanhf(gg);
      const float hn = so * tanhf(cn);
      const int j = wg * 8 + uj;
      if (t < SS - 1){
        sC[ub][uj] = cn;
        const unsigned short h0 = f2bf(hn);
        const unsigned short l0 = f2bf(hn - bf2f(h0));
        unsigned short* hw = hbuf + (size_t)((t & 1) ^ 1) * 32768;
        const int off = (((j >> 5) * 4 + ((j >> 3) & 3)) * 4 + (ub >> 4)) * 128
                        + (ub & 15) * 8 + (j & 7);
        unsigned short* pH = hw + off;
        unsigned short* pL = hw + 16384 + off;
        const unsigned vh = h0, vl = l0;
        asm volatile("global_store_short %0, %1, off sc0 sc1" :: "v"(pH), "v"(vh) : "memory");
        asm volatile("global_store_short %0, %1, off sc0 sc1" :: "v"(pL), "v"(vl) : "memory");
      } else {
        out[ub * 512 + j]       = hn;
        out[ub * 512 + 256 + j] = cn;
      }
    }

    // ---- release: h stores ack'd at IF, then set own flag (no RMW) ----
    if (t < SS - 1){
      asm volatile("s_waitcnt vmcnt(0)" ::: "memory");
      __syncthreads();
      if (tid == 0){
        const int val = t + 1;
        int* fp = &flags[wg];
        asm volatile("global_store_dword %0, %1, off sc0 sc1" :: "v"(fp), "v"(val) : "memory");
      }
    }
  }
}

extern "C" void kernel_launch(void* const* d_in, const int* in_sizes, int n_in,
                              void* d_out, int out_size, void* d_ws, size_t ws_size,
                              hipStream_t stream)
{
  const int*   input  = (const int*)  d_in[0];
  const int*   assign = (const int*)  d_in[1];
  const float* emb    = (const float*)d_in[2];
  const float* Wih    = (const float*)d_in[3];
  const float* Whh    = (const float*)d_in[4];
  const float* bih    = (const float*)d_in[5];
  const float* bhh    = (const float*)d_in[6];
  float* out = (float*)d_out;
  char*  ws  = (char*)d_ws;

  zero_flags_kernel<<<1, 256, 0, stream>>>((int*)ws);
  float* xg = (float*)(ws + WS_XG_OFF);
  xproj_kernel<<<256, TPB, 0, stream>>>(input, assign, emb, Wih, bih, bhh, xg);
  mlstm_rec_kernel<<<NWG, TPB, 0, stream>>>(input, assign, Whh, out, ws);
}